// Round 9
// baseline (21008.879 us; speedup 1.0000x reference)
//
#include <hip/hip_runtime.h>
#include <hip/hip_fp16.h>
#include <math.h>

// Problem dims (fixed)
#define T_SEQ 4096
#define DIN   64
#define DM    1024
#define G4    4096              // 4*DM gate rows
#define LSTRIDE_W ((size_t)G4 * DM)   // per-layer Wih/Whh stride
#define LSTRIDE_B ((size_t)G4)        // per-layer bias stride

typedef unsigned long long u64;
typedef unsigned int u32;

__device__ __forceinline__ float sigmoidf_(float x) {
    return 1.0f / (1.0f + __expf(-x));
}
__device__ __forceinline__ float tanhf_(float x) {
    float ax = fabsf(x);
    float e  = __expf(-2.0f * ax);
    float t  = (1.0f - e) / (1.0f + e);
    return copysignf(t, x);
}
__device__ __forceinline__ float lrelu_(float x) {
    return x > 0.0f ? x : 0.01f * x;
}

// pack two fp32 -> one u32 of two f16 (v_cvt_pkrtz_f16_f32)
__device__ __forceinline__ u32 pk2_(float x, float y) {
    typedef __fp16 hv2 __attribute__((ext_vector_type(2)));
    union { hv2 h; u32 u; } c;
    c.h = __builtin_amdgcn_cvt_pkrtz(x, y);
    return c.u;
}
// fused f16-pair dot-accumulate: acc += a.x*b.x + a.y*b.y
#if __has_builtin(__builtin_amdgcn_fdot2)
__device__ __forceinline__ float d2a_(u32 a, u32 b, float acc) {
    typedef __fp16 hv2 __attribute__((ext_vector_type(2)));
    union { u32 u; hv2 h; } ua, ub;
    ua.u = a; ub.u = b;
    return __builtin_amdgcn_fdot2(ua.h, ub.h, acc, false);
}
#else
__device__ __forceinline__ float d2a_(u32 a, u32 b, float acc) {
    union { u32 u; __half2 h; } ua, ub;
    ua.u = a; ub.u = b;
    float2 fa = __half22float2(ua.h);
    float2 fb = __half22float2(ub.h);
    return acc + fa.x * fb.x + fa.y * fb.y;
}
#endif
__device__ __forceinline__ float dot8a_(uint4 q, uint4 h, float acc) {
    acc = d2a_(q.x, h.x, acc);
    acc = d2a_(q.y, h.y, acc);
    acc = d2a_(q.z, h.z, acc);
    acc = d2a_(q.w, h.w, acc);
    return acc;
}

// ---------------------------------------------------------------------------
// K1: x[t,d] = leaky_relu(sum_k inp[t,k]*W1[d,k] + b1[d]);  grid=4096, block=256
// ---------------------------------------------------------------------------
__global__ __launch_bounds__(256) void k_input(const float* __restrict__ inp,
                                               const float* __restrict__ W1,
                                               const float* __restrict__ b1,
                                               float* __restrict__ x) {
    __shared__ float s_in[DIN];
    const int t   = blockIdx.x;
    const int tid = threadIdx.x;
    if (tid < DIN) s_in[tid] = inp[(size_t)t * DIN + tid];
    __syncthreads();
#pragma unroll
    for (int q = 0; q < 4; q++) {
        const int d = tid + q * 256;
        const float4* wr = (const float4*)(W1 + (size_t)d * DIN);
        float acc = 0.0f;
#pragma unroll
        for (int e = 0; e < 16; e++) {
            float4 w = wr[e];
            acc += w.x * s_in[e * 4 + 0] + w.y * s_in[e * 4 + 1] +
                   w.z * s_in[e * 4 + 2] + w.w * s_in[e * 4 + 3];
        }
        acc += b1[d];
        x[(size_t)t * DM + d] = lrelu_(acc);
    }
}

// ---------------------------------------------------------------------------
// K2: xg[m,n] = sum_k x[m,k]*Wih0[n,k] + (bih0[n]+bhh0[n])
// 128x128 tile, BK=16, 256 threads, 8x8 per thread.
// ---------------------------------------------------------------------------
__global__ __launch_bounds__(256) void k_gemm(const float* __restrict__ A,
                                              const float* __restrict__ B,
                                              const float* __restrict__ bih,
                                              const float* __restrict__ bhh,
                                              float* __restrict__ C) {
    const int K = DM;
    __shared__ float As[16][132];
    __shared__ float Bs[16][132];
    const int tid = threadIdx.x;
    const int m0 = blockIdx.y * 128, n0 = blockIdx.x * 128;
    const int tx = tid & 15, ty = tid >> 4;
    const int lr = tid >> 1;
    const int lc = (tid & 1) * 8;

    float acc[8][8] = {};
    const float4* ag = (const float4*)(A + (size_t)(m0 + lr) * K + lc);
    const float4* bg = (const float4*)(B + (size_t)(n0 + lr) * K + lc);

    for (int k0 = 0; k0 < K; k0 += 16) {
        float4 a0 = ag[0], a1 = ag[1];
        float4 b0 = bg[0], b1v = bg[1];
        ag += 4; bg += 4;
        __syncthreads();
        As[lc + 0][lr] = a0.x; As[lc + 1][lr] = a0.y; As[lc + 2][lr] = a0.z; As[lc + 3][lr] = a0.w;
        As[lc + 4][lr] = a1.x; As[lc + 5][lr] = a1.y; As[lc + 6][lr] = a1.z; As[lc + 7][lr] = a1.w;
        Bs[lc + 0][lr] = b0.x; Bs[lc + 1][lr] = b0.y; Bs[lc + 2][lr] = b0.z; Bs[lc + 3][lr] = b0.w;
        Bs[lc + 4][lr] = b1v.x; Bs[lc + 5][lr] = b1v.y; Bs[lc + 6][lr] = b1v.z; Bs[lc + 7][lr] = b1v.w;
        __syncthreads();
#pragma unroll
        for (int k = 0; k < 16; k++) {
            float a[8], b[8];
            *(float4*)&a[0] = *(const float4*)&As[k][ty * 8 + 0];
            *(float4*)&a[4] = *(const float4*)&As[k][ty * 8 + 4];
            *(float4*)&b[0] = *(const float4*)&Bs[k][tx * 8 + 0];
            *(float4*)&b[4] = *(const float4*)&Bs[k][tx * 8 + 4];
#pragma unroll
            for (int i = 0; i < 8; i++)
#pragma unroll
                for (int j = 0; j < 8; j++)
                    acc[i][j] += a[i] * b[j];
        }
    }
    float bj[8];
#pragma unroll
    for (int j = 0; j < 8; j++) {
        int n = n0 + tx * 8 + j;
        bj[j] = bih[n] + bhh[n];
    }
#pragma unroll
    for (int i = 0; i < 8; i++) {
        float4 v0, v1;
        v0.x = acc[i][0] + bj[0]; v0.y = acc[i][1] + bj[1];
        v0.z = acc[i][2] + bj[2]; v0.w = acc[i][3] + bj[3];
        v1.x = acc[i][4] + bj[4]; v1.y = acc[i][5] + bj[5];
        v1.z = acc[i][6] + bj[6]; v1.w = acc[i][7] + bj[7];
        float* cp = C + (size_t)(m0 + ty * 8 + i) * G4 + n0 + tx * 8;
        *(float4*)(cp + 0) = v0;
        *(float4*)(cp + 4) = v1;
    }
}

// ---------------------------------------------------------------------------
// K3: fused 2-layer pipelined scan, critical-path split + load pipelining (R9).
// vs R8: (1) xg[t+1] prefetched a round ahead (HBM latency drains at B3,
// off the h0 chain); (2) speculative tag-loads: sl0 for round t+1 issued
// right after the h0 publish, sl1 for round t issued at round top -- on tag
// hit the critical path pays no MALL latency; miss falls back to retry loop;
// (3) own-WG h values bypass global via small LDS arrays (own0/own1);
// (4) v_dot2_f32_f16 for the GEMV inner op.
// Protocol unchanged: tagged u64 slots, parity dbuf, relaxed agent atomics.
// ---------------------------------------------------------------------------
__global__ __launch_bounds__(256, 1) void k_scan2(
        const float* __restrict__ xg,     // T x 4096 layer-0 preacts
        const float* __restrict__ Wih1,
        const float* __restrict__ Whh0,
        const float* __restrict__ Whh1,
        const float* __restrict__ bih1,
        const float* __restrict__ bhh1,
        u64* sl0,                         // [2][1024] tagged h0 slots
        u64* sl1,                         // [2][1024] tagged h1 slots
        float* __restrict__ out) {
    const int tid = threadIdx.x;
    const int w   = blockIdx.x;
    const int wv  = tid >> 6;             // wave 0..3
    const int ln  = tid & 63;             // lane
    const int rs  = tid >> 4;             // row slot 0..15 (g=rs>>2, s=rs&3)
    const int ck  = tid & 15;             // k-chunk of 64
    const int g   = rs >> 2, s = rs & 3;
    const int r   = g * DM + w * 4 + s;   // global gate row (same for all 3 mats)

    __shared__ uint4 wlds[3][4][8][64];   // 96 KB f16 weights
    __shared__ uint4 hst0[2][16][9];      // h0 staged (f16), parity dbuf
    __shared__ uint4 hst1[2][16][9];      // h1 staged (f16), parity dbuf
    __shared__ float gp0[2][16], gp1[2][16], gp2[2][16];
    __shared__ float own0[4], own1[4];    // own-WG h bypass (no global trip)

    // ---- prologue: pack f16 weights into LDS (self-storage) ----
    {
        const float* srcs[3] = { Whh0, Wih1, Whh1 };
#pragma unroll
        for (int m = 0; m < 3; m++) {
            const float4* gw = (const float4*)(srcs[m] + (size_t)r * DM + ck * 64);
#pragma unroll
            for (int e = 0; e < 8; e++) {
                float4 a = gw[e * 2 + 0];
                float4 b = gw[e * 2 + 1];
                uint4 q;
                q.x = pk2_(a.x, a.y); q.y = pk2_(a.z, a.w);
                q.z = pk2_(b.x, b.y); q.w = pk2_(b.z, b.w);
                wlds[m][wv][e][ln] = q;
            }
        }
    }
    // layer-1 gate biases (state threads 4..7; s1 = tid-4)
    float b1s[4] = {0.f, 0.f, 0.f, 0.f};
    if (tid >= 4 && tid < 8) {
        const int s1 = tid - 4;
#pragma unroll
        for (int gg = 0; gg < 4; gg++)
            b1s[gg] = bih1[gg * DM + w * 4 + s1] + bhh1[gg * DM + w * 4 + s1];
    }
    if (tid < 4) own0[tid] = 0.f;
    if (tid >= 4 && tid < 8) own1[tid - 4] = 0.f;
    __syncthreads();

    const int stc = tid >> 4;             // stage chunk for h[tid*4..+4)
    const int sto = tid & 15;             // u64 index within chunk row
    float c0 = 0.f, h0v = 0.f, c1 = 0.f, h1v = 0.f;

    // pipelined state
    u64 sa0 = 0, sa1 = 0, sa2 = 0, sa3 = 0;   // spec sl0 (for next round)
    u64 sb0 = 0, sb1 = 0, sb2 = 0, sb3 = 0;   // spec sl1 (for this round)
    float xgv_cur = 0.f;
    if (ck == 0) xgv_cur = xg[r];             // row t=0

    for (int t = 0; t <= T_SEQ; t++) {
        const int par = t & 1;

        // early-issue sl1 spec for THIS round's phase B (tag t): ~phase-A of slack
        if (t > 0) {
            const u64* p1 = sl1 + (size_t)par * 1024 + tid * 4;
            sb0 = __hip_atomic_load(p1 + 0, __ATOMIC_RELAXED, __HIP_MEMORY_SCOPE_AGENT);
            sb1 = __hip_atomic_load(p1 + 1, __ATOMIC_RELAXED, __HIP_MEMORY_SCOPE_AGENT);
            sb2 = __hip_atomic_load(p1 + 2, __ATOMIC_RELAXED, __HIP_MEMORY_SCOPE_AGENT);
            sb3 = __hip_atomic_load(p1 + 3, __ATOMIC_RELAXED, __HIP_MEMORY_SCOPE_AGENT);
        }

        // ================= Phase A: critical h0 chain =================
        if (t == 0) {
            ((u64*)&hst0[0][stc][0])[sto] = 0ull;
        } else if (tid == w) {
            // own WG's h0 from LDS (written at last round's publish)
            u32 q0 = pk2_(own0[0], own0[1]);
            u32 q1 = pk2_(own0[2], own0[3]);
            ((u64*)&hst0[par][stc][0])[sto] = ((u64)q1 << 32) | q0;
        } else {
            const u32 want = (u32)t;
            bool ok = ((u32)(sa0 >> 32) == want) & ((u32)(sa1 >> 32) == want) &
                      ((u32)(sa2 >> 32) == want) & ((u32)(sa3 >> 32) == want);
            if (!ok) {
                const u64* p0 = sl0 + (size_t)par * 1024 + tid * 4;
                do {
                    sa0 = __hip_atomic_load(p0 + 0, __ATOMIC_RELAXED, __HIP_MEMORY_SCOPE_AGENT);
                    sa1 = __hip_atomic_load(p0 + 1, __ATOMIC_RELAXED, __HIP_MEMORY_SCOPE_AGENT);
                    sa2 = __hip_atomic_load(p0 + 2, __ATOMIC_RELAXED, __HIP_MEMORY_SCOPE_AGENT);
                    sa3 = __hip_atomic_load(p0 + 3, __ATOMIC_RELAXED, __HIP_MEMORY_SCOPE_AGENT);
                    ok = ((u32)(sa0 >> 32) == want) & ((u32)(sa1 >> 32) == want) &
                         ((u32)(sa2 >> 32) == want) & ((u32)(sa3 >> 32) == want);
                } while (!ok);
            }
            u32 q0 = pk2_(__uint_as_float((u32)sa0), __uint_as_float((u32)sa1));
            u32 q1 = pk2_(__uint_as_float((u32)sa2), __uint_as_float((u32)sa3));
            ((u64*)&hst0[par][stc][0])[sto] = ((u64)q1 << 32) | q0;
        }
        __syncthreads();   // B1: hst0[par] visible

        // dot0: Whh0 row r · h0[t-1]
        float acc0 = 0.f;
#pragma unroll
        for (int e = 0; e < 8; e++) {
            acc0 = dot8a_(wlds[0][wv][e][ln], hst0[par][ck][e], acc0);
        }
#pragma unroll
        for (int m = 1; m <= 8; m <<= 1) acc0 += __shfl_xor(acc0, m, 64);
        if (ck == 0) gp0[par][rs] = xgv_cur + acc0;
        __syncthreads();   // B2: gp0 visible

        if (tid < 4 && t < T_SEQ) {
            float pi = gp0[par][0 + tid];
            float pf = gp0[par][4 + tid];
            float pg = gp0[par][8 + tid];
            float po = gp0[par][12 + tid];
            c0 = sigmoidf_(pf) * c0 + sigmoidf_(pi) * tanhf_(pg);
            h0v = sigmoidf_(po) * tanhf_(c0);
            own0[tid] = h0v;
            u64 v = ((u64)(u32)(t + 1) << 32) | (u64)__float_as_uint(h0v);
            __hip_atomic_store(sl0 + (size_t)((t + 1) & 1) * 1024 + w * 4 + tid,
                               v, __ATOMIC_RELAXED, __HIP_MEMORY_SCOPE_AGENT);
        }

        // post-publish issues: sl0 spec for round t+1, xg prefetch for t+1.
        // These drain at B3 (shadow region), not on the h0 chain.
        float xgv_next = 0.f;
        if (t < T_SEQ) {
            const u64* p0 = sl0 + (size_t)((t + 1) & 1) * 1024 + tid * 4;
            sa0 = __hip_atomic_load(p0 + 0, __ATOMIC_RELAXED, __HIP_MEMORY_SCOPE_AGENT);
            sa1 = __hip_atomic_load(p0 + 1, __ATOMIC_RELAXED, __HIP_MEMORY_SCOPE_AGENT);
            sa2 = __hip_atomic_load(p0 + 2, __ATOMIC_RELAXED, __HIP_MEMORY_SCOPE_AGENT);
            sa3 = __hip_atomic_load(p0 + 3, __ATOMIC_RELAXED, __HIP_MEMORY_SCOPE_AGENT);
            if (ck == 0 && t + 1 < T_SEQ) xgv_next = xg[(size_t)(t + 1) * G4 + r];
        }

        // ================= Phase B: shadow h1 work =================
        if (t == 0) {
            ((u64*)&hst1[0][stc][0])[sto] = 0ull;
        } else if (tid == w) {
            u32 q0 = pk2_(own1[0], own1[1]);
            u32 q1 = pk2_(own1[2], own1[3]);
            ((u64*)&hst1[par][stc][0])[sto] = ((u64)q1 << 32) | q0;
        } else {
            const u32 want = (u32)t;
            bool ok = ((u32)(sb0 >> 32) == want) & ((u32)(sb1 >> 32) == want) &
                      ((u32)(sb2 >> 32) == want) & ((u32)(sb3 >> 32) == want);
            if (!ok) {
                const u64* p1 = sl1 + (size_t)par * 1024 + tid * 4;
                do {
                    sb0 = __hip_atomic_load(p1 + 0, __ATOMIC_RELAXED, __HIP_MEMORY_SCOPE_AGENT);
                    sb1 = __hip_atomic_load(p1 + 1, __ATOMIC_RELAXED, __HIP_MEMORY_SCOPE_AGENT);
                    sb2 = __hip_atomic_load(p1 + 2, __ATOMIC_RELAXED, __HIP_MEMORY_SCOPE_AGENT);
                    sb3 = __hip_atomic_load(p1 + 3, __ATOMIC_RELAXED, __HIP_MEMORY_SCOPE_AGENT);
                    ok = ((u32)(sb0 >> 32) == want) & ((u32)(sb1 >> 32) == want) &
                         ((u32)(sb2 >> 32) == want) & ((u32)(sb3 >> 32) == want);
                } while (!ok);
            }
            u32 q0 = pk2_(__uint_as_float((u32)sb0), __uint_as_float((u32)sb1));
            u32 q1 = pk2_(__uint_as_float((u32)sb2), __uint_as_float((u32)sb3));
            ((u64*)&hst1[par][stc][0])[sto] = ((u64)q1 << 32) | q0;
        }
        __syncthreads();   // B3: hst1[par] visible (drains xg/sa issues too)

        // dot1: Wih1 row r · h0[t-1];  dot2: Whh1 row r · h1[t-2]
        float acc1 = 0.f, acc2 = 0.f;
#pragma unroll
        for (int e = 0; e < 8; e++) {
            acc1 = dot8a_(wlds[1][wv][e][ln], hst0[par][ck][e], acc1);
            acc2 = dot8a_(wlds[2][wv][e][ln], hst1[par][ck][e], acc2);
        }
#pragma unroll
        for (int m = 1; m <= 8; m <<= 1) {
            acc1 += __shfl_xor(acc1, m, 64);
            acc2 += __shfl_xor(acc2, m, 64);
        }
        if (ck == 0) { gp1[par][rs] = acc1; gp2[par][rs] = acc2; }
        __syncthreads();   // B4: gp1/gp2 visible

        if (tid >= 4 && tid < 8) {
            const int s1 = tid - 4;
            if (t > 0) {
                float pi = gp1[par][0 + s1]  + gp2[par][0 + s1]  + b1s[0];
                float pf = gp1[par][4 + s1]  + gp2[par][4 + s1]  + b1s[1];
                float pg = gp1[par][8 + s1]  + gp2[par][8 + s1]  + b1s[2];
                float po = gp1[par][12 + s1] + gp2[par][12 + s1] + b1s[3];
                c1 = sigmoidf_(pf) * c1 + sigmoidf_(pi) * tanhf_(pg);
                h1v = sigmoidf_(po) * tanhf_(c1);
            }
            if (t < T_SEQ) {
                own1[s1] = h1v;
                u64 v = ((u64)(u32)(t + 1) << 32) | (u64)__float_as_uint(h1v);
                __hip_atomic_store(sl1 + (size_t)((t + 1) & 1) * 1024 + w * 4 + s1,
                                   v, __ATOMIC_RELAXED, __HIP_MEMORY_SCOPE_AGENT);
            }
        }
        xgv_cur = xgv_next;
        // parity double-buffers + B1..B4 separate all LDS read/write pairs;
        // own0/own1 write(post-B2/post-B4) vs read(next round pre-B1/pre-B3)
        // are separated by >=2 barriers each.
    }

    if (tid >= 4 && tid < 8) {
        out[w * 4 + (tid - 4)] = lrelu_(h1v);   // h1[T-1]
    }
}

// ---------------------------------------------------------------------------
extern "C" void kernel_launch(void* const* d_in, const int* in_sizes, int n_in,
                              void* d_out, int out_size, void* d_ws, size_t ws_size,
                              hipStream_t stream) {
    const float* inp = (const float*)d_in[0];   // 4096 x 64
    const float* W1  = (const float*)d_in[1];   // 1024 x 64
    const float* b1  = (const float*)d_in[2];   // 1024
    const float* Wih = (const float*)d_in[3];   // 2 x 4096 x 1024
    const float* Whh = (const float*)d_in[4];   // 2 x 4096 x 1024
    const float* bih = (const float*)d_in[5];   // 2 x 4096
    const float* bhh = (const float*)d_in[6];   // 2 x 4096
    float* out = (float*)d_out;                 // 1024

    // workspace layout
    float* x   = (float*)d_ws;                          // 4096*1024 f32
    float* xg  = x + (size_t)T_SEQ * DM;                // 4096*4096 f32
    u64*   sl0 = (u64*)(xg + (size_t)T_SEQ * G4);       // 2*1024 u64
    u64*   sl1 = sl0 + 2048;                            // 2*1024 u64
    (void)in_sizes; (void)n_in; (void)out_size; (void)ws_size;

    // Phase 1: input projection
    k_input<<<dim3(T_SEQ), dim3(256), 0, stream>>>(inp, W1, b1, x);

    // Phase 2: xg = x @ Wih0^T + (bih0+bhh0)
    k_gemm<<<dim3(32, 32), dim3(256), 0, stream>>>(x, Wih, bih, bhh, xg);

    // Phase 3: fused 2-layer pipelined scan (critical-path split + spec polls)
    k_scan2<<<dim3(256), dim3(256), 0, stream>>>(
        xg, Wih + LSTRIDE_W, Whh, Whh + LSTRIDE_W,
        bih + LSTRIDE_B, bhh + LSTRIDE_B, sl0, sl1, out);
}

// Round 10
// 11259.911 us; speedup vs baseline: 1.8658x; 1.8658x over previous
//
#include <hip/hip_runtime.h>
#include <hip/hip_fp16.h>
#include <math.h>

// Problem dims (fixed)
#define T_SEQ 4096
#define DIN   64
#define DM    1024
#define G4    4096              // 4*DM gate rows
#define LSTRIDE_W ((size_t)G4 * DM)   // per-layer Wih/Whh stride
#define LSTRIDE_B ((size_t)G4)        // per-layer bias stride

typedef unsigned long long u64;
typedef unsigned int u32;

__device__ __forceinline__ float sigmoidf_(float x) {
    return 1.0f / (1.0f + __expf(-x));
}
__device__ __forceinline__ float tanhf_(float x) {
    float ax = fabsf(x);
    float e  = __expf(-2.0f * ax);
    float t  = (1.0f - e) / (1.0f + e);
    return copysignf(t, x);
}
__device__ __forceinline__ float lrelu_(float x) {
    return x > 0.0f ? x : 0.01f * x;
}

// pack two fp32 -> one u32 of two f16 (v_cvt_pkrtz_f16_f32)
__device__ __forceinline__ u32 pk2_(float x, float y) {
    typedef __fp16 hv2 __attribute__((ext_vector_type(2)));
    union { hv2 h; u32 u; } c;
    c.h = __builtin_amdgcn_cvt_pkrtz(x, y);
    return c.u;
}
// fused f16-pair dot-accumulate: acc += a.x*b.x + a.y*b.y
#if __has_builtin(__builtin_amdgcn_fdot2)
__device__ __forceinline__ float d2a_(u32 a, u32 b, float acc) {
    typedef __fp16 hv2 __attribute__((ext_vector_type(2)));
    union { u32 u; hv2 h; } ua, ub;
    ua.u = a; ub.u = b;
    return __builtin_amdgcn_fdot2(ua.h, ub.h, acc, false);
}
#else
__device__ __forceinline__ float d2a_(u32 a, u32 b, float acc) {
    union { u32 u; __half2 h; } ua, ub;
    ua.u = a; ub.u = b;
    float2 fa = __half22float2(ua.h);
    float2 fb = __half22float2(ub.h);
    return acc + fa.x * fb.x + fa.y * fb.y;
}
#endif
__device__ __forceinline__ float dot8a_(uint4 q, uint4 h, float acc) {
    acc = d2a_(q.x, h.x, acc);
    acc = d2a_(q.y, h.y, acc);
    acc = d2a_(q.z, h.z, acc);
    acc = d2a_(q.w, h.w, acc);
    return acc;
}

// ---------------------------------------------------------------------------
// K1: x[t,d] = leaky_relu(sum_k inp[t,k]*W1[d,k] + b1[d]);  grid=4096, block=256
// ---------------------------------------------------------------------------
__global__ __launch_bounds__(256) void k_input(const float* __restrict__ inp,
                                               const float* __restrict__ W1,
                                               const float* __restrict__ b1,
                                               float* __restrict__ x) {
    __shared__ float s_in[DIN];
    const int t   = blockIdx.x;
    const int tid = threadIdx.x;
    if (tid < DIN) s_in[tid] = inp[(size_t)t * DIN + tid];
    __syncthreads();
#pragma unroll
    for (int q = 0; q < 4; q++) {
        const int d = tid + q * 256;
        const float4* wr = (const float4*)(W1 + (size_t)d * DIN);
        float acc = 0.0f;
#pragma unroll
        for (int e = 0; e < 16; e++) {
            float4 w = wr[e];
            acc += w.x * s_in[e * 4 + 0] + w.y * s_in[e * 4 + 1] +
                   w.z * s_in[e * 4 + 2] + w.w * s_in[e * 4 + 3];
        }
        acc += b1[d];
        x[(size_t)t * DM + d] = lrelu_(acc);
    }
}

// ---------------------------------------------------------------------------
// K2: xg[m,n] = sum_k x[m,k]*Wih0[n,k] + (bih0[n]+bhh0[n])
// 128x128 tile, BK=16, 256 threads, 8x8 per thread.
// ---------------------------------------------------------------------------
__global__ __launch_bounds__(256) void k_gemm(const float* __restrict__ A,
                                              const float* __restrict__ B,
                                              const float* __restrict__ bih,
                                              const float* __restrict__ bhh,
                                              float* __restrict__ C) {
    const int K = DM;
    __shared__ float As[16][132];
    __shared__ float Bs[16][132];
    const int tid = threadIdx.x;
    const int m0 = blockIdx.y * 128, n0 = blockIdx.x * 128;
    const int tx = tid & 15, ty = tid >> 4;
    const int lr = tid >> 1;
    const int lc = (tid & 1) * 8;

    float acc[8][8] = {};
    const float4* ag = (const float4*)(A + (size_t)(m0 + lr) * K + lc);
    const float4* bg = (const float4*)(B + (size_t)(n0 + lr) * K + lc);

    for (int k0 = 0; k0 < K; k0 += 16) {
        float4 a0 = ag[0], a1 = ag[1];
        float4 b0 = bg[0], b1v = bg[1];
        ag += 4; bg += 4;
        __syncthreads();
        As[lc + 0][lr] = a0.x; As[lc + 1][lr] = a0.y; As[lc + 2][lr] = a0.z; As[lc + 3][lr] = a0.w;
        As[lc + 4][lr] = a1.x; As[lc + 5][lr] = a1.y; As[lc + 6][lr] = a1.z; As[lc + 7][lr] = a1.w;
        Bs[lc + 0][lr] = b0.x; Bs[lc + 1][lr] = b0.y; Bs[lc + 2][lr] = b0.z; Bs[lc + 3][lr] = b0.w;
        Bs[lc + 4][lr] = b1v.x; Bs[lc + 5][lr] = b1v.y; Bs[lc + 6][lr] = b1v.z; Bs[lc + 7][lr] = b1v.w;
        __syncthreads();
#pragma unroll
        for (int k = 0; k < 16; k++) {
            float a[8], b[8];
            *(float4*)&a[0] = *(const float4*)&As[k][ty * 8 + 0];
            *(float4*)&a[4] = *(const float4*)&As[k][ty * 8 + 4];
            *(float4*)&b[0] = *(const float4*)&Bs[k][tx * 8 + 0];
            *(float4*)&b[4] = *(const float4*)&Bs[k][tx * 8 + 4];
#pragma unroll
            for (int i = 0; i < 8; i++)
#pragma unroll
                for (int j = 0; j < 8; j++)
                    acc[i][j] += a[i] * b[j];
        }
    }
    float bj[8];
#pragma unroll
    for (int j = 0; j < 8; j++) {
        int n = n0 + tx * 8 + j;
        bj[j] = bih[n] + bhh[n];
    }
#pragma unroll
    for (int i = 0; i < 8; i++) {
        float4 v0, v1;
        v0.x = acc[i][0] + bj[0]; v0.y = acc[i][1] + bj[1];
        v0.z = acc[i][2] + bj[2]; v0.w = acc[i][3] + bj[3];
        v1.x = acc[i][4] + bj[4]; v1.y = acc[i][5] + bj[5];
        v1.z = acc[i][6] + bj[6]; v1.w = acc[i][7] + bj[7];
        float* cp = C + (size_t)(m0 + ty * 8 + i) * G4 + n0 + tx * 8;
        *(float4*)(cp + 0) = v0;
        *(float4*)(cp + 4) = v1;
    }
}

// ---------------------------------------------------------------------------
// K3: fused 2-layer scan, R10 = R8 protocol (demand polls, NO speculation)
// + wave-per-state remap: row slot rs = 4*s + g (s = rs>>2 = wave index).
// After the intra-16-lane reduce, all 4 gate preacts of state s live in
// lanes {0,16,32,48} of wave s -> lane 0 gathers with 3 in-wave shuffles and
// does gate math + publish with NO barrier and NO gp LDS round-trip.
// Barriers/round: 2 (was 4).  xg prefetched post-publish (16 loads/WG, tiny).
// R9 lesson: speculative slot polls (~0% hit) double MALL pressure -> 1.6x
// regression; demand-paced retry loops only.
// ---------------------------------------------------------------------------
__global__ __launch_bounds__(256, 1) void k_scan2(
        const float* __restrict__ xg,     // T x 4096 layer-0 preacts
        const float* __restrict__ Wih1,
        const float* __restrict__ Whh0,
        const float* __restrict__ Whh1,
        const float* __restrict__ bih1,
        const float* __restrict__ bhh1,
        u64* sl0,                         // [2][1024] tagged h0 slots
        u64* sl1,                         // [2][1024] tagged h1 slots
        float* __restrict__ out) {
    const int tid = threadIdx.x;
    const int w   = blockIdx.x;
    const int wv  = tid >> 6;             // wave 0..3 == state index s
    const int ln  = tid & 63;             // lane
    const int rs  = tid >> 4;             // row slot 0..15
    const int ck  = tid & 15;             // k-chunk of 64
    const int s_i = rs >> 2;              // state (== wv)
    const int g_i = rs & 3;               // gate
    const int r   = g_i * DM + w * 4 + s_i;   // global gate row

    __shared__ uint4 wlds[3][4][8][64];   // 96 KB f16 weights (self-storage)
    __shared__ uint4 hst0[2][16][9];      // h0 staged (f16), parity dbuf
    __shared__ uint4 hst1[2][16][9];      // h1 staged (f16), parity dbuf
    __shared__ float own0[4], own1[4];    // own-WG h bypass (no global trip)

    // ---- prologue: pack f16 weights into LDS (self-storage) ----
    {
        const float* srcs[3] = { Whh0, Wih1, Whh1 };
#pragma unroll
        for (int m = 0; m < 3; m++) {
            const float4* gw = (const float4*)(srcs[m] + (size_t)r * DM + ck * 64);
#pragma unroll
            for (int e = 0; e < 8; e++) {
                float4 a = gw[e * 2 + 0];
                float4 b = gw[e * 2 + 1];
                uint4 q;
                q.x = pk2_(a.x, a.y); q.y = pk2_(a.z, a.w);
                q.z = pk2_(b.x, b.y); q.w = pk2_(b.z, b.w);
                wlds[m][wv][e][ln] = q;
            }
        }
    }
    // layer-1 gate biases: lane 0 of wave s holds b1s[g] for state s
    float b1s[4] = {0.f, 0.f, 0.f, 0.f};
    if (ln == 0) {
#pragma unroll
        for (int gg = 0; gg < 4; gg++)
            b1s[gg] = bih1[gg * DM + w * 4 + wv] + bhh1[gg * DM + w * 4 + wv];
    }
    if (tid < 4) { own0[tid] = 0.f; own1[tid] = 0.f; }
    __syncthreads();

    const int stc = tid >> 4;             // stage chunk for h[tid*4..+4)
    const int sto = tid & 15;             // u64 index within chunk row
    float c0 = 0.f, h0v = 0.f, c1 = 0.f, h1v = 0.f;

    float xgv_cur = 0.f;
    if (ck == 0) xgv_cur = xg[r];         // row t=0

    for (int t = 0; t <= T_SEQ; t++) {
        const int par = t & 1;

        // ================= Phase A: critical h0 chain =================
        if (t == 0) {
            ((u64*)&hst0[0][stc][0])[sto] = 0ull;
        } else if (tid == w) {
            u32 q0 = pk2_(own0[0], own0[1]);
            u32 q1 = pk2_(own0[2], own0[3]);
            ((u64*)&hst0[par][stc][0])[sto] = ((u64)q1 << 32) | q0;
        } else {
            const u64* p0 = sl0 + (size_t)par * 1024 + tid * 4;
            const u32 want = (u32)t;
            u64 a0, a1, a2, a3;
            for (;;) {
                a0 = __hip_atomic_load(p0 + 0, __ATOMIC_RELAXED, __HIP_MEMORY_SCOPE_AGENT);
                a1 = __hip_atomic_load(p0 + 1, __ATOMIC_RELAXED, __HIP_MEMORY_SCOPE_AGENT);
                a2 = __hip_atomic_load(p0 + 2, __ATOMIC_RELAXED, __HIP_MEMORY_SCOPE_AGENT);
                a3 = __hip_atomic_load(p0 + 3, __ATOMIC_RELAXED, __HIP_MEMORY_SCOPE_AGENT);
                bool ok = ((u32)(a0 >> 32) == want) & ((u32)(a1 >> 32) == want) &
                          ((u32)(a2 >> 32) == want) & ((u32)(a3 >> 32) == want);
                if (ok) break;
            }
            u32 q0 = pk2_(__uint_as_float((u32)a0), __uint_as_float((u32)a1));
            u32 q1 = pk2_(__uint_as_float((u32)a2), __uint_as_float((u32)a3));
            ((u64*)&hst0[par][stc][0])[sto] = ((u64)q1 << 32) | q0;
        }
        __syncthreads();   // B1: hst0[par] visible

        // dot0: Whh0 row r · h0[t-1]
        float acc0 = 0.f;
#pragma unroll
        for (int e = 0; e < 8; e++) {
            acc0 = dot8a_(wlds[0][wv][e][ln], hst0[par][ck][e], acc0);
        }
#pragma unroll
        for (int m = 1; m <= 8; m <<= 1) acc0 += __shfl_xor(acc0, m, 64);
        if (ck == 0) acc0 += xgv_cur;     // lanes 0,16,32,48 hold gate preacts

        // in-wave gather + gate math + publish (lane 0 of wave s = state s)
        {
            float pi = __shfl(acc0, 0, 64);
            float pf = __shfl(acc0, 16, 64);
            float pg = __shfl(acc0, 32, 64);
            float po = __shfl(acc0, 48, 64);
            if (ln == 0 && t < T_SEQ) {
                c0 = sigmoidf_(pf) * c0 + sigmoidf_(pi) * tanhf_(pg);
                h0v = sigmoidf_(po) * tanhf_(c0);
                own0[wv] = h0v;
                u64 v = ((u64)(u32)(t + 1) << 32) | (u64)__float_as_uint(h0v);
                __hip_atomic_store(sl0 + (size_t)((t + 1) & 1) * 1024 + w * 4 + wv,
                                   v, __ATOMIC_RELAXED, __HIP_MEMORY_SCOPE_AGENT);
            }
        }

        // xg prefetch for t+1 (16 tiny loads/WG; drains by next use, off-chain)
        float xgv_next = 0.f;
        if (ck == 0 && t + 1 < T_SEQ) xgv_next = xg[(size_t)(t + 1) * G4 + r];

        // ================= Phase B: shadow h1 work =================
        if (t == 0) {
            ((u64*)&hst1[0][stc][0])[sto] = 0ull;
        } else if (tid == w) {
            u32 q0 = pk2_(own1[0], own1[1]);
            u32 q1 = pk2_(own1[2], own1[3]);
            ((u64*)&hst1[par][stc][0])[sto] = ((u64)q1 << 32) | q0;
        } else {
            const u64* p1 = sl1 + (size_t)par * 1024 + tid * 4;
            const u32 want = (u32)t;
            u64 d0, d1, d2, d3;
            for (;;) {
                d0 = __hip_atomic_load(p1 + 0, __ATOMIC_RELAXED, __HIP_MEMORY_SCOPE_AGENT);
                d1 = __hip_atomic_load(p1 + 1, __ATOMIC_RELAXED, __HIP_MEMORY_SCOPE_AGENT);
                d2 = __hip_atomic_load(p1 + 2, __ATOMIC_RELAXED, __HIP_MEMORY_SCOPE_AGENT);
                d3 = __hip_atomic_load(p1 + 3, __ATOMIC_RELAXED, __HIP_MEMORY_SCOPE_AGENT);
                bool ok = ((u32)(d0 >> 32) == want) & ((u32)(d1 >> 32) == want) &
                          ((u32)(d2 >> 32) == want) & ((u32)(d3 >> 32) == want);
                if (ok) break;
            }
            u32 q0 = pk2_(__uint_as_float((u32)d0), __uint_as_float((u32)d1));
            u32 q1 = pk2_(__uint_as_float((u32)d2), __uint_as_float((u32)d3));
            ((u64*)&hst1[par][stc][0])[sto] = ((u64)q1 << 32) | q0;
        }
        __syncthreads();   // B3: hst1[par] visible

        // dot1: Wih1 row r · h0[t-1];  dot2: Whh1 row r · h1[t-2]
        float acc1 = 0.f, acc2 = 0.f;
#pragma unroll
        for (int e = 0; e < 8; e++) {
            acc1 = dot8a_(wlds[1][wv][e][ln], hst0[par][ck][e], acc1);
            acc2 = dot8a_(wlds[2][wv][e][ln], hst1[par][ck][e], acc2);
        }
#pragma unroll
        for (int m = 1; m <= 8; m <<= 1) {
            acc1 += __shfl_xor(acc1, m, 64);
            acc2 += __shfl_xor(acc2, m, 64);
        }
        // in-wave gather + gate + publish for layer 1 (lane 0 of wave s)
        {
            float pi = __shfl(acc1, 0, 64)  + __shfl(acc2, 0, 64);
            float pf = __shfl(acc1, 16, 64) + __shfl(acc2, 16, 64);
            float pg = __shfl(acc1, 32, 64) + __shfl(acc2, 32, 64);
            float po = __shfl(acc1, 48, 64) + __shfl(acc2, 48, 64);
            if (ln == 0) {
                if (t > 0) {
                    pi += b1s[0]; pf += b1s[1]; pg += b1s[2]; po += b1s[3];
                    c1 = sigmoidf_(pf) * c1 + sigmoidf_(pi) * tanhf_(pg);
                    h1v = sigmoidf_(po) * tanhf_(c1);
                }
                if (t < T_SEQ) {
                    own1[wv] = h1v;
                    u64 v = ((u64)(u32)(t + 1) << 32) | (u64)__float_as_uint(h1v);
                    __hip_atomic_store(sl1 + (size_t)((t + 1) & 1) * 1024 + w * 4 + wv,
                                       v, __ATOMIC_RELAXED, __HIP_MEMORY_SCOPE_AGENT);
                }
            }
        }
        xgv_cur = xgv_next;
        // Hazards: hst0/hst1 parity dbuf + B1/B3 separate all read/write
        // pairs (>=2 barriers between conflicting rounds). own0 write
        // (post-B1 region, t) vs read (pre-B1, t+1): B3(t) intervenes.
        // own1 write (post-B3, t) vs read (pre-B3, t+1): B1(t+1) intervenes.
    }

    if (ln == 0) {
        out[w * 4 + wv] = lrelu_(h1v);    // h1[T-1]
    }
}

// ---------------------------------------------------------------------------
extern "C" void kernel_launch(void* const* d_in, const int* in_sizes, int n_in,
                              void* d_out, int out_size, void* d_ws, size_t ws_size,
                              hipStream_t stream) {
    const float* inp = (const float*)d_in[0];   // 4096 x 64
    const float* W1  = (const float*)d_in[1];   // 1024 x 64
    const float* b1  = (const float*)d_in[2];   // 1024
    const float* Wih = (const float*)d_in[3];   // 2 x 4096 x 1024
    const float* Whh = (const float*)d_in[4];   // 2 x 4096 x 1024
    const float* bih = (const float*)d_in[5];   // 2 x 4096
    const float* bhh = (const float*)d_in[6];   // 2 x 4096
    float* out = (float*)d_out;                 // 1024

    // workspace layout
    float* x   = (float*)d_ws;                          // 4096*1024 f32
    float* xg  = x + (size_t)T_SEQ * DM;                // 4096*4096 f32
    u64*   sl0 = (u64*)(xg + (size_t)T_SEQ * G4);       // 2*1024 u64
    u64*   sl1 = sl0 + 2048;                            // 2*1024 u64
    (void)in_sizes; (void)n_in; (void)out_size; (void)ws_size;

    // Phase 1: input projection
    k_input<<<dim3(T_SEQ), dim3(256), 0, stream>>>(inp, W1, b1, x);

    // Phase 2: xg = x @ Wih0^T + (bih0+bhh0)
    k_gemm<<<dim3(32, 32), dim3(256), 0, stream>>>(x, Wih, bih, bhh, xg);

    // Phase 3: fused 2-layer scan (wave-per-state, 2 barriers/round)
    k_scan2<<<dim3(256), dim3(256), 0, stream>>>(
        xg, Wih + LSTRIDE_W, Whh, Whh + LSTRIDE_W,
        bih + LSTRIDE_B, bhh + LSTRIDE_B, sl0, sl1, out);
}